// Round 9
// baseline (299.479 us; speedup 1.0000x reference)
//
#include <hip/hip_runtime.h>
#include <cstdint>
#include <cstddef>

#define BATCH 8192
#define KC 8
#define NC 1024
#define DC 256
// Single-pass f16 GEMM: measured flag-rate ~1.0% at TAU=0.10 (cnt~640).
// Flagged rows re-resolved exactly in fp64 by refine_scan/pick.
#define TAU 0.10f

typedef __attribute__((ext_vector_type(8))) _Float16 half8;
typedef __attribute__((ext_vector_type(4))) _Float16 half4;
typedef __attribute__((ext_vector_type(4))) float floatx4;

__device__ __forceinline__ void async_load16(const void* g, void* l) {
    __builtin_amdgcn_global_load_lds((const __attribute__((address_space(1))) uint32_t*)g,
                                     (__attribute__((address_space(3))) uint32_t*)l, 16, 0, 0);
}
__device__ __forceinline__ unsigned sortable(float v) {
    unsigned u = __float_as_uint(v);
    return u ^ (unsigned)(((int)u >> 31) | 0x80000000);
}
__device__ __forceinline__ float unsortable(unsigned ks) {
    unsigned u = (ks & 0x80000000u) ? (ks ^ 0x80000000u) : ~ks;
    return __uint_as_float(u);
}

// XOR-swizzled 16KB LDS sub-tile (128 rows x 64 halfs): row r, 16B chunk c at slot c^(r&7)
__device__ __forceinline__ int lidx(int r, int c) {
    return (r >> 3) * 1024 + (r & 7) * 128 + ((c ^ (r & 7)) * 16);
}
__device__ __forceinline__ half8 ldsr(const char* base, int r, int c) {
    return *(const half8*)(base + lidx(r, c));
}

// ---------------------------------------------------------------------------
// P: entries -> Eh f16 [row][256]; eef = fp32(|e|^2 via fp64)
// ---------------------------------------------------------------------------
__global__ __launch_bounds__(256) void prep_e_kernel(const float* __restrict__ entries,
                                                     _Float16* __restrict__ Ecat,
                                                     float* __restrict__ eef) {
    int wave = threadIdx.x >> 6, lane = threadIdx.x & 63;
    int row = blockIdx.x * 4 + wave;            // [0, 8192) = k*NC + n
    float4 v = ((const float4*)(entries + (size_t)row * DC))[lane];
    half4 h;
    h.x = (_Float16)v.x; h.y = (_Float16)v.y; h.z = (_Float16)v.z; h.w = (_Float16)v.w;
    *(half4*)(Ecat + (size_t)row * 256 + lane * 4) = h;
    double s = (double)v.x * v.x + (double)v.y * v.y + (double)v.z * v.z + (double)v.w * v.w;
    #pragma unroll
    for (int off = 32; off > 0; off >>= 1) s += __shfl_down(s, off, 64);
    if (lane == 0) eef[row] = (float)s;
}

// ---------------------------------------------------------------------------
// GEMM: grid 1024 (k = blk&7 -> XCD-pinned; g = blk>>3: bt = g>>1, nh = g&1).
// Block: 128 rows x 512 cols (nh half of N), K-step 64, 4 waves x 32 rows.
// OCCUPANCY via N-split: LDS ~35KB (2 x 16KB bufs + eef) -> 3-4 blocks/CU,
// launch_bounds(256,3) -> 12 waves/CU (was 8). M=32/wave FLOP:LDS ratio and
// the verified swizzle geometry preserved. Gather/loss/flag moved OUT (see
// resolve_kernel): vq ends with per-row-half top-2 -> global s01/g2min.
// ---------------------------------------------------------------------------
__global__ __launch_bounds__(256, 3) void vq_gemm(const float* __restrict__ x,
                                                  const _Float16* __restrict__ Ecat,
                                                  const float* __restrict__ eef,
                                                  unsigned long long* __restrict__ s01,
                                                  unsigned* __restrict__ g2min) {
    __shared__ alignas(16) char Bst[2][16384];   // 2-ring: 128 cols x 64 dims each
    __shared__ float eef_lds[512];

    const int t = threadIdx.x;
    const int k  = blockIdx.x & 7;
    const int g  = blockIdx.x >> 3;
    const int b0 = (g >> 1) * 128;
    const int nh = g & 1;
    const int ncol0 = nh * 512;
    const int w = t >> 6, lane = t & 63;
    const int quad = lane >> 4, col = lane & 15;
    const int rl = lane >> 3;
    const int cs = (lane & 7) ^ rl;

    ((float2*)eef_lds)[t] = ((const float2*)(eef + (size_t)k * NC + ncol0))[t];

    // ---- A fragments: full K=256 in registers, plain f16 ----
    half8 Ah[2][8];
    #pragma unroll
    for (int mi = 0; mi < 2; ++mi) {
        const float* xrow = x + ((size_t)(b0 + w * 32 + mi * 16 + col) * KC + k) * DC + quad * 8;
        #pragma unroll
        for (int ks = 0; ks < 8; ++ks) {
            float4 u0 = *(const float4*)(xrow + ks * 32);
            float4 u1 = *(const float4*)(xrow + ks * 32 + 4);
            float f[8] = {u0.x, u0.y, u0.z, u0.w, u1.x, u1.y, u1.z, u1.w};
            half8 h;
            #pragma unroll
            for (int j = 0; j < 8; ++j) h[j] = (_Float16)f[j];
            Ah[mi][ks] = h;
        }
    }

    const char* EcatK = (const char*)(Ecat + (size_t)k * NC * 256);   // 512B per col

    // Stage (nt, ds): cols ncol0+nt*128..+127, dims ds*64..+63 -> Bst[buf].
    // 16 groups of 1KB (8 cols x 64 dims, swizzled); 4 loads per wave.
    #define ISSUE_B(nt_, ds_, buf_)                                                      \
        {                                                                                \
            char* bb_ = Bst[buf_];                                                       \
            _Pragma("unroll")                                                            \
            for (int j = 0; j < 4; ++j) {                                                \
                int grp_ = w * 4 + j;                                                    \
                const char* src_ = EcatK                                                 \
                    + (size_t)(ncol0 + (nt_) * 128 + grp_ * 8 + rl) * 512                \
                    + (ds_) * 128 + cs * 16;                                             \
                async_load16(src_, bb_ + grp_ * 1024 + lane * 16);                       \
            }                                                                            \
        }

    // One stage: drain, barrier, prefetch stage+1, 16 ds_read_b128 + 32 MFMA.
    // ds_ is a LITERAL (compile-time A indices). buf = ds&1; prefetch (ds+1)&1.
    #define STAGE(nt_, ds_, DOISS_, nnt_, nds_)                                          \
        {                                                                                \
            asm volatile("s_waitcnt vmcnt(0)" ::: "memory");                             \
            __builtin_amdgcn_s_barrier();                                                \
            __builtin_amdgcn_sched_barrier(0);                                           \
            if (DOISS_) { ISSUE_B((nnt_), (nds_), ((ds_) + 1) & 1); }                    \
            const char* Bs_ = Bst[(ds_) & 1];                                            \
            __builtin_amdgcn_s_setprio(1);                                               \
            _Pragma("unroll")                                                            \
            for (int kk = 0; kk < 2; ++kk) {                                             \
                const int cb = kk * 4 + quad;                                            \
                _Pragma("unroll")                                                        \
                for (int ni = 0; ni < 8; ++ni) {                                         \
                    half8 bh = ldsr(Bs_, ni * 16 + col, cb);                             \
                    acc[0][ni] = __builtin_amdgcn_mfma_f32_16x16x32_f16(                 \
                        Ah[0][(ds_) * 2 + kk], bh, acc[0][ni], 0, 0, 0);                 \
                    acc[1][ni] = __builtin_amdgcn_mfma_f32_16x16x32_f16(                 \
                        Ah[1][(ds_) * 2 + kk], bh, acc[1][ni], 0, 0, 0);                 \
                }                                                                        \
            }                                                                            \
            __builtin_amdgcn_s_setprio(0);                                               \
        }

    // ---- lane-local running top-2 per (mi,reg) across all nt ----
    float lv1[8], lv2[8]; int li1[8];
    #pragma unroll
    for (int q = 0; q < 8; ++q) { lv1[q] = 1e30f; lv2[q] = 1e30f; li1[q] = 0; }

    ISSUE_B(0, 0, 0);

    for (int nt = 0; nt < 4; ++nt) {
        const int n0 = nt * 128;
        floatx4 acc[2][8] = {};
        STAGE(nt, 0, 1, nt, 1)
        STAGE(nt, 1, 1, nt, 2)
        STAGE(nt, 2, 1, nt, 3)
        STAGE(nt, 3, (nt < 3), nt + 1, 0)
        // ---- per-nt epilogue: lane-local top-2 update (no shuffles) ----
        float ev[8];
        #pragma unroll
        for (int ni = 0; ni < 8; ++ni) ev[ni] = eef_lds[n0 + ni * 16 + col];
        #pragma unroll
        for (int mi = 0; mi < 2; ++mi) {
            #pragma unroll
            for (int reg = 0; reg < 4; ++reg) {
                const int q = mi * 4 + reg;
                #pragma unroll
                for (int ni = 0; ni < 8; ++ni) {
                    float val = fmaf(-2.0f, acc[mi][ni][reg], ev[ni]);
                    int n = n0 + ni * 16 + col;
                    bool lt1 = val < lv1[q];
                    bool lt2 = val < lv2[q];
                    float nv2 = lt1 ? lv1[q] : (lt2 ? val : lv2[q]);
                    li1[q] = lt1 ? n : li1[q];
                    lv1[q] = lt1 ? val : lv1[q];
                    lv2[q] = nv2;
                }
            }
        }
    }

    // ---- final: one 16-lane butterfly per (mi,reg); col==0 lane publishes ----
    #pragma unroll
    for (int q = 0; q < 8; ++q) {
        float v1 = lv1[q], v2 = lv2[q]; int i1 = li1[q];
        #pragma unroll
        for (int off = 1; off < 16; off <<= 1) {
            float o1 = __shfl_xor(v1, off, 16);
            float o2 = __shfl_xor(v2, off, 16);
            int   oi = __shfl_xor(i1, off, 16);
            bool sw = o1 < v1;
            float hi = sw ? v1 : o1;          // max(v1, o1)
            v1 = sw ? o1 : v1;
            i1 = sw ? oi : i1;
            v2 = fminf(fminf(v2, o2), hi);
        }
        if (col == 0) {
            const int mi = q >> 2, reg = q & 3;
            int row = w * 32 + mi * 16 + quad * 4 + reg;
            int rid = (b0 + row) * KC + k;
            s01[(size_t)nh * 65536 + rid] =
                ((unsigned long long)sortable(v1) << 32) | (unsigned)(ncol0 + i1);
            atomicMin(&g2min[rid], sortable(v2));
        }
    }
    #undef STAGE
    #undef ISSUE_B
}

// ---------------------------------------------------------------------------
// RESOLVE: merge the two nh halves exactly (v1 = min; v2 = min(g2, max of
// the two v1s)); flag near-ties into per-k lists; for resolved rows do the
// coalesced out_q gather + exact fp64 loss (contiguous 128-row blocks ->
// fully coalesced x / out_q, unlike vq's k-strided layout).
// ---------------------------------------------------------------------------
__global__ __launch_bounds__(256) void resolve_kernel(const float* __restrict__ x,
                                                      const float* __restrict__ entries,
                                                      const unsigned long long* __restrict__ s01,
                                                      const unsigned* __restrict__ g2min,
                                                      float* __restrict__ out_idx,
                                                      float* __restrict__ out_q,
                                                      double* __restrict__ partial,
                                                      int* __restrict__ flag_list,
                                                      int* __restrict__ flag_cnt) {
    __shared__ int idx_lds[128];
    __shared__ double red[256];
    const int t = threadIdx.x;
    const int r0 = blockIdx.x * 128;

    if (t < 128) {
        int rid = r0 + t;
        unsigned long long sa = s01[rid], sb = s01[65536 + rid];
        unsigned long long lo = sa < sb ? sa : sb;
        unsigned long long hi = sa < sb ? sb : sa;
        unsigned v2u = g2min[rid];
        unsigned hv = (unsigned)(hi >> 32);
        if (hv < v2u) v2u = hv;
        float v1 = unsortable((unsigned)(lo >> 32));
        float v2 = unsortable(v2u);
        if (v2 - v1 < TAU) {
            int k = rid & 7;
            int pos = atomicAdd(&flag_cnt[k], 1);
            flag_list[k * 8192 + pos] = rid;
            idx_lds[t] = -1;
        } else {
            int n = (int)(lo & 0xFFFFFFFFull);
            idx_lds[t] = n;
            out_idx[rid] = (float)n;
        }
    }
    __syncthreads();

    double s = 0.0;
    #pragma unroll
    for (int rr = 0; rr < 8; ++rr) {
        int r = rr * 16 + (t >> 4);
        int c = t & 15;
        int n = idx_lds[r];
        if (n >= 0) {
            int rid2 = r0 + r;
            const float4* xp = (const float4*)(x + (size_t)rid2 * DC);
            const float4* ep = (const float4*)(entries + (((size_t)(rid2 & 7)) * NC + n) * DC);
            float4* op = (float4*)(out_q + (size_t)rid2 * DC);
            #pragma unroll
            for (int j = 0; j < 4; ++j) {
                int ci = j * 16 + c;
                float4 xv = xp[ci], evv = ep[ci];
                op[ci] = evv;
                double d0 = (double)xv.x - evv.x, d1 = (double)xv.y - evv.y;
                double d2 = (double)xv.z - evv.z, d3 = (double)xv.w - evv.w;
                s += d0 * d0 + d1 * d1 + d2 * d2 + d3 * d3;
            }
        }
    }
    red[t] = s;
    __syncthreads();
    for (int off2 = 128; off2 > 0; off2 >>= 1) {
        if (t < off2) red[t] += red[t + off2];
        __syncthreads();
    }
    if (t == 0) partial[blockIdx.x] = red[0];
}

// ---------------------------------------------------------------------------
// REF-SCAN (k-grouped): item = (k, 16-row group, 128-entry segment).
// ---------------------------------------------------------------------------
__global__ __launch_bounds__(256) void refine_scan(const float* __restrict__ x,
                                                   const float* __restrict__ entries,
                                                   const int* __restrict__ flag_list,
                                                   const int* __restrict__ flag_cnt,
                                                   unsigned long long* __restrict__ slots) {
    __shared__ alignas(16) char tileb[128 * 256];   // 128 entries x 64 dims (swizzled)
    __shared__ float xs[16 * 260];                  // 16 rows x 256 dims (pad 260)
    const int t = threadIdx.x;
    const int r = t >> 4, eg = t & 15;
    for (int it = blockIdx.x; it < 8 * 8 * 512; it += gridDim.x) {
        const int k = it & 7, seg = (it >> 3) & 7, g = it >> 6;
        const int cnt_k = flag_cnt[k];
        if (g * 16 >= cnt_k) continue;
        const int nrows = min(16, cnt_k - g * 16);
        {
            const int rr = t >> 4, c16 = t & 15;
            const int rid2 = flag_list[k * 8192 + g * 16 + ((rr < nrows) ? rr : 0)];
            const float4* xp = (const float4*)(x + (size_t)rid2 * DC);
            #pragma unroll
            for (int j = 0; j < 4; ++j) {
                float4 v = xp[c16 * 4 + j];
                *(float4*)(xs + rr * 260 + (c16 * 4 + j) * 4) = v;
            }
        }
        double acc[8] = {};
        #pragma unroll
        for (int c = 0; c < 4; ++c) {
            {
                const int c16 = t & 15;
                #pragma unroll
                for (int it2 = 0; it2 < 8; ++it2) {
                    int row = it2 * 16 + (t >> 4);
                    float4 v = *(const float4*)(entries
                        + ((size_t)k * NC + seg * 128 + row) * DC + c * 64 + c16 * 4);
                    *(float4*)(tileb + row * 256 + ((c16 ^ (row >> 3)) * 16)) = v;
                }
            }
            __syncthreads();
            const float* xpp = xs + r * 260 + c * 64;
            #pragma unroll 4
            for (int dq = 0; dq < 16; ++dq) {
                float4 xv = *(const float4*)(xpp + dq * 4);
                #pragma unroll
                for (int j = 0; j < 8; ++j) {
                    int e = eg * 8 + j;
                    float4 evv = *(const float4*)(tileb + e * 256 + ((dq ^ eg) * 16));
                    double d0 = (double)xv.x - (double)evv.x;
                    double d1 = (double)xv.y - (double)evv.y;
                    double d2 = (double)xv.z - (double)evv.z;
                    double d3 = (double)xv.w - (double)evv.w;
                    acc[j] += d0 * d0 + d1 * d1 + d2 * d2 + d3 * d3;
                }
            }
            __syncthreads();
        }
        double best = acc[0]; int bn = seg * 128 + eg * 8;
        #pragma unroll
        for (int j = 1; j < 8; ++j) {
            if (acc[j] < best) { best = acc[j]; bn = seg * 128 + eg * 8 + j; }
        }
        unsigned long long key =
            ((unsigned long long)__double_as_longlong(best) & ~1023ull)
            | (unsigned long long)(unsigned)bn;
        #pragma unroll
        for (int off = 1; off < 16; off <<= 1) {
            unsigned long long o = __shfl_xor(key, off, 16);
            key = o < key ? o : key;
        }
        if (eg == 0 && r < nrows) {
            atomicMin(&slots[k * 8192 + g * 16 + r], key);
        }
    }
}

// ---------------------------------------------------------------------------
// REF-PICK: decode winner from slot, write idx, coalesced out_q, loss add.
// ---------------------------------------------------------------------------
__global__ __launch_bounds__(256) void refine_pick(const float* __restrict__ entries,
                                                   const int* __restrict__ flag_list,
                                                   const int* __restrict__ flag_cnt,
                                                   const unsigned long long* __restrict__ slots,
                                                   float* __restrict__ out_idx,
                                                   float* __restrict__ out_q,
                                                   double* __restrict__ refAcc) {
    const int t = threadIdx.x;
    for (int idx = blockIdx.x; idx < 8 * 8192; idx += gridDim.x) {
        const int k = idx >> 13, pos = idx & 8191;
        if (pos >= flag_cnt[k]) continue;
        unsigned long long key = slots[idx];
        int n = (int)(key & 1023ull);
        int rid = flag_list[idx];
        out_q[(size_t)rid * DC + t] = entries[((size_t)k * NC + n) * DC + t];
        if (t == 0) {
            out_idx[rid] = (float)n;
            atomicAdd(refAcc, __longlong_as_double((long long)(key & ~1023ull)));
        }
    }
}

__global__ __launch_bounds__(256) void finalize_kernel(const double* __restrict__ partial,
                                                       const double* __restrict__ refAcc,
                                                       float* __restrict__ out) {
    __shared__ double red[256];
    const int t = threadIdx.x;
    double s = 0.0;
    for (int i = t; i < 512; i += 256) s += partial[i];
    red[t] = s;
    __syncthreads();
    for (int off = 128; off > 0; off >>= 1) {
        if (t < off) red[t] += red[t + off];
        __syncthreads();
    }
    if (t == 0) {
        double L = (red[0] + *refAcc) * (1.0 / 65536.0);
        out[(size_t)BATCH * KC * DC + BATCH * KC + 0] = (float)L;
        out[(size_t)BATCH * KC * DC + BATCH * KC + 1] = (float)(0.25 * L);
    }
}

extern "C" void kernel_launch(void* const* d_in, const int* in_sizes, int n_in,
                              void* d_out, int out_size, void* d_ws, size_t ws_size,
                              hipStream_t stream) {
    const float* x       = (const float*)d_in[0];   // [8192, 8, 256]
    const float* entries = (const float*)d_in[1];   // [8, 1024, 256]
    float* out = (float*)d_out;

    char* ws = (char*)d_ws;
    int*      flag_cnt  = (int*)ws;                         // +0: int[8]
    double*   refAcc    = (double*)(ws + 64);               // +64
    double*   partial   = (double*)(ws + 4096);             // 512 doubles
    float*    eef       = (float*)(ws + 65536);             // 32 KB
    int*      flag_list = (int*)(ws + 131072);              // 8 lists x 8192
    _Float16* Ecat      = (_Float16*)(ws + 1048576);        // 4 MB
    unsigned long long* slots = (unsigned long long*)(ws + 5242880);  // 512 KB
    unsigned* g2min     = (unsigned*)(ws + 5767168);        // 256 KB
    unsigned long long* s01 = (unsigned long long*)(ws + 6291456);    // 1 MB

    float* out_q   = out;                                   // 16,777,216 floats
    float* out_idx = out + (size_t)BATCH * KC * DC;         // 65,536 floats

    hipMemsetAsync(ws, 0, 128, stream);                     // flag_cnt[8] + refAcc
    hipMemsetAsync(slots, 0xFF, (size_t)65536 * 8, stream); // u64 max
    hipMemsetAsync(g2min, 0xFF, (size_t)65536 * 4, stream); // u32 max
    prep_e_kernel<<<KC * NC / 4, 256, 0, stream>>>(entries, Ecat, eef);
    vq_gemm<<<1024, 256, 0, stream>>>(x, Ecat, eef, s01, g2min);
    resolve_kernel<<<512, 256, 0, stream>>>(x, entries, s01, g2min, out_idx,
                                            out_q, partial, flag_list, flag_cnt);
    refine_scan<<<512, 256, 0, stream>>>(x, entries, flag_list, flag_cnt, slots);
    refine_pick<<<512, 256, 0, stream>>>(entries, flag_list, flag_cnt, slots,
                                         out_idx, out_q, refAcc);
    finalize_kernel<<<1, 256, 0, stream>>>(partial, refAcc, out);
}